// Round 1
// baseline (488.782 us; speedup 1.0000x reference)
//
#include <hip/hip_runtime.h>
#include <math.h>

#define B 2
#define N 512
#define DIM 256
#define HEADS 8
#define DHEAD 32
#define INNER 256
#define DEPTH 2
#define SCALE 0.17677669529663687f

// ---------------- encode: nodes = [x,t] @ W_enc ----------------
__global__ void k_encode(const float* __restrict__ x, const float* __restrict__ t,
                         const float* __restrict__ Wenc, float* __restrict__ nodes) {
    int bn = blockIdx.x;            // 0..B*N-1
    int d  = threadIdx.x;           // 0..255
    float x0 = x[bn*3+0], x1 = x[bn*3+1], x2 = x[bn*3+2], tt = t[bn];
    nodes[bn*DIM + d] = x0*Wenc[0*DIM+d] + x1*Wenc[1*DIM+d] + x2*Wenc[2*DIM+d] + tt*Wenc[3*DIM+d];
}

// ---------------- pairwise distances ----------------
__global__ void k_dist(const float* __restrict__ x, float* __restrict__ dist) {
    int b = blockIdx.x / N, i = blockIdx.x % N, j = threadIdx.x;  // block 512
    const float* xi = x + (b*N+i)*3;
    const float* xj = x + (b*N+j)*3;
    float d0 = xi[0]-xj[0], d1 = xi[1]-xj[1], d2 = xi[2]-xj[2];
    float s = d0*d0 + d1*d1 + d2*d2;
    dist[(size_t)(b*N+i)*N + j] = (s > 0.f) ? sqrtf(s) : 0.f;
}

// ------------- LN + QKV proj + rotary + (q.we, q.be) -------------
__global__ void k_ln_qkv(const float* __restrict__ nodes,
                         const float* __restrict__ ln_g, const float* __restrict__ ln_b,
                         const float* __restrict__ Wq, const float* __restrict__ bq,
                         const float* __restrict__ Wkv, const float* __restrict__ bkv,
                         const float* __restrict__ We, const float* __restrict__ be,
                         float* __restrict__ qbuf, float* __restrict__ kbuf, float* __restrict__ vbuf,
                         float* __restrict__ qwe, float* __restrict__ qbe, int layer) {
    __shared__ float h[DIM];
    __shared__ float red[DIM];
    __shared__ float qs[DIM], ks[DIM];
    int bn = blockIdx.x;            // b*N + i
    int d  = threadIdx.x;           // 0..255
    int b  = bn >> 9;
    int i  = bn & (N-1);

    float xv = nodes[bn*DIM + d];
    red[d] = xv; __syncthreads();
    for (int s = 128; s > 0; s >>= 1) { if (d < s) red[d] += red[d+s]; __syncthreads(); }
    float mean = red[0] * (1.0f/DIM);
    __syncthreads();
    float c = xv - mean;
    red[d] = c*c; __syncthreads();
    for (int s = 128; s > 0; s >>= 1) { if (d < s) red[d] += red[d+s]; __syncthreads(); }
    float var = red[0] * (1.0f/DIM);
    float hv = c * (1.0f/sqrtf(var + 1e-5f)) * ln_g[layer*DIM+d] + ln_b[layer*DIM+d];
    h[d] = hv;
    __syncthreads();

    const float* Wql  = Wq  + (size_t)layer*DIM*INNER;
    const float* Wkvl = Wkv + (size_t)layer*DIM*2*INNER;
    float qacc = bq[layer*INNER + d];
    float kacc = bkv[layer*2*INNER + d];
    float vacc = bkv[layer*2*INNER + INNER + d];
    #pragma unroll 4
    for (int kk = 0; kk < DIM; ++kk) {
        float hk = h[kk];
        qacc += hk * Wql [kk*INNER + d];
        kacc += hk * Wkvl[kk*2*INNER + d];
        vacc += hk * Wkvl[kk*2*INNER + INNER + d];
    }

    // rotary: head-dim index dd in [0,32); angle = i * invfreq[dd%16]
    int dd = d & 31;
    int jj = dd & 15;
    double invf = 1.0 / pow(10000.0, (double)(2*jj) / 32.0);
    double ang  = (double)i * invf;
    float ca = (float)cos(ang), sa = (float)sin(ang);

    qs[d] = qacc; ks[d] = kacc;
    __syncthreads();
    int partner = (dd < 16) ? d + 16 : d - 16;
    float sgn   = (dd < 16) ? -1.f : 1.f;
    float qrot = qacc*ca + sgn*qs[partner]*sa;
    float krot = kacc*ca + sgn*ks[partner]*sa;

    qbuf[bn*INNER + d] = qrot;
    kbuf[bn*INNER + d] = krot;
    vbuf[bn*INNER + d] = vacc;

    __syncthreads();                 // all partner reads done
    qs[d] = qrot * We[layer*INNER + d];
    ks[d] = qrot * be[layer*INNER + d];
    __syncthreads();
    if (d < HEADS) {
        float sw = 0.f, sb = 0.f;
        #pragma unroll
        for (int u = 0; u < DHEAD; ++u) { sw += qs[d*DHEAD+u]; sb += ks[d*DHEAD+u]; }
        qwe[(b*HEADS + d)*N + i] = sw;
        qbe[(b*HEADS + d)*N + i] = sb;
    }
}

// ------------- attention: one wave per (b,h,i) row -------------
__global__ void k_attn(const float* __restrict__ qbuf, const float* __restrict__ kbuf,
                       const float* __restrict__ vbuf,
                       const float* __restrict__ qwe, const float* __restrict__ qbe,
                       const float* __restrict__ dist,
                       const float* __restrict__ We, const float* __restrict__ be,
                       float* __restrict__ attnout, int layer) {
    int bid = blockIdx.x;           // b*H*N + h*N + i
    int i = bid & (N-1);
    int h = (bid >> 9) & (HEADS-1);
    int b = bid >> 12;
    int lane = threadIdx.x;         // 0..63

    __shared__ float p[N];
    __shared__ float qsh[DHEAD];
    if (lane < DHEAD) qsh[lane] = qbuf[(b*N+i)*INNER + h*DHEAD + lane];
    __syncthreads();

    float qw = qwe[(b*HEADS+h)*N + i];
    float qb = qbe[(b*HEADS+h)*N + i];
    const float* drow = dist + (size_t)(b*N+i)*N;

    float simv[8];
    float mx = -1e30f;
    #pragma unroll
    for (int t = 0; t < 8; ++t) {
        int j = lane + t*64;
        const float* krow = kbuf + (b*N+j)*INNER + h*DHEAD;
        float s = 0.f;
        #pragma unroll
        for (int d2 = 0; d2 < DHEAD; ++d2) s += qsh[d2]*krow[d2];
        s += drow[j]*qw + qb;
        s *= SCALE;
        simv[t] = s;
        mx = fmaxf(mx, s);
    }
    #pragma unroll
    for (int off = 32; off; off >>= 1) mx = fmaxf(mx, __shfl_xor(mx, off));

    float lsum = 0.f, ldsum = 0.f;
    #pragma unroll
    for (int t = 0; t < 8; ++t) {
        int j = lane + t*64;
        float e = expf(simv[t] - mx);
        p[j] = e;
        lsum  += e;
        ldsum += e * drow[j];
    }
    #pragma unroll
    for (int off = 32; off; off >>= 1) { lsum += __shfl_xor(lsum, off); ldsum += __shfl_xor(ldsum, off); }
    __syncthreads();

    // PV: lane = d2 + 32*half; each half sums 256 j's
    int d2 = lane & 31, half = lane >> 5;
    float acc = 0.f;
    int j0 = half*256;
    for (int j = j0; j < j0+256; ++j)
        acc += p[j] * vbuf[(b*N+j)*INNER + h*DHEAD + d2];
    acc += __shfl_xor(acc, 32);
    if (half == 0) {
        float invl = 1.0f/lsum;
        float ad = ldsum*invl;
        float outv = acc*invl + ad*We[layer*INNER + h*DHEAD + d2] + be[layer*INNER + h*DHEAD + d2];
        attnout[(b*N+i)*INNER + h*DHEAD + d2] = outv;
    }
}

// ------------- output proj + scalar gate + residual -------------
__global__ void k_proj_gate(const float* __restrict__ attnout,
                            const float* __restrict__ Wo, const float* __restrict__ bo,
                            const float* __restrict__ Wg,
                            float* __restrict__ nodes, int layer) {
    __shared__ float a[INNER];
    __shared__ float red[DIM];
    int bn = blockIdx.x, d = threadIdx.x;
    a[d] = attnout[bn*INNER + d];
    __syncthreads();
    const float* Wol = Wo + (size_t)layer*INNER*DIM;
    float o = bo[layer*DIM + d];
    #pragma unroll 4
    for (int kk = 0; kk < INNER; ++kk) o += a[kk] * Wol[kk*DIM + d];
    float nd = nodes[bn*DIM + d];
    const float* Wgl = Wg + layer*3*DIM;
    red[d] = o*Wgl[d] + nd*Wgl[DIM+d] + (o-nd)*Wgl[2*DIM+d];
    __syncthreads();
    for (int s = 128; s > 0; s >>= 1) { if (d < s) red[d] += red[d+s]; __syncthreads(); }
    float gate = 1.0f/(1.0f + expf(-red[0]));
    nodes[bn*DIM + d] = o*gate + nd*(1.0f-gate);
}

// ---------------- decode: out = nodes @ W_dec ----------------
__global__ void k_decode(const float* __restrict__ nodes, const float* __restrict__ Wdec,
                         float* __restrict__ out) {
    __shared__ float red[3][DIM];
    int bn = blockIdx.x, d = threadIdx.x;
    float nd = nodes[bn*DIM + d];
    red[0][d] = nd * Wdec[d*3+0];
    red[1][d] = nd * Wdec[d*3+1];
    red[2][d] = nd * Wdec[d*3+2];
    __syncthreads();
    for (int s = 128; s > 0; s >>= 1) {
        if (d < s) { red[0][d]+=red[0][d+s]; red[1][d]+=red[1][d+s]; red[2][d]+=red[2][d+s]; }
        __syncthreads();
    }
    if (d < 3) out[bn*3 + d] = red[d][0];
}

extern "C" void kernel_launch(void* const* d_in, const int* in_sizes, int n_in,
                              void* d_out, int out_size, void* d_ws, size_t ws_size,
                              hipStream_t stream) {
    const float* x     = (const float*)d_in[0];
    const float* t     = (const float*)d_in[1];
    const float* W_enc = (const float*)d_in[2];
    const float* W_dec = (const float*)d_in[3];
    const float* ln_g  = (const float*)d_in[4];
    const float* ln_b  = (const float*)d_in[5];
    const float* Wq    = (const float*)d_in[6];
    const float* bq    = (const float*)d_in[7];
    const float* Wkv   = (const float*)d_in[8];
    const float* bkv   = (const float*)d_in[9];
    const float* We    = (const float*)d_in[10];
    const float* be    = (const float*)d_in[11];
    const float* Wo    = (const float*)d_in[12];
    const float* bo    = (const float*)d_in[13];
    const float* Wg    = (const float*)d_in[14];
    float* out = (float*)d_out;

    float* ws = (float*)d_ws;
    float* nodes   = ws;                       // B*N*DIM      = 262144
    float* dist    = nodes   + B*N*DIM;        // B*N*N        = 524288
    float* qbuf    = dist    + B*N*N;          // B*N*INNER
    float* kbuf    = qbuf    + B*N*INNER;
    float* vbuf    = kbuf    + B*N*INNER;
    float* qwe     = vbuf    + B*N*INNER;      // B*HEADS*N    = 8192
    float* qbe     = qwe     + B*HEADS*N;
    float* attnout = qbe     + B*HEADS*N;      // B*N*INNER

    k_encode<<<B*N, DIM, 0, stream>>>(x, t, W_enc, nodes);
    k_dist  <<<B*N, N,   0, stream>>>(x, dist);
    for (int l = 0; l < DEPTH; ++l) {
        k_ln_qkv<<<B*N, DIM, 0, stream>>>(nodes, ln_g, ln_b, Wq, bq, Wkv, bkv, We, be,
                                          qbuf, kbuf, vbuf, qwe, qbe, l);
        k_attn<<<B*HEADS*N, 64, 0, stream>>>(qbuf, kbuf, vbuf, qwe, qbe, dist, We, be,
                                             attnout, l);
        k_proj_gate<<<B*N, DIM, 0, stream>>>(attnout, Wo, bo, Wg, nodes, l);
    }
    k_decode<<<B*N, DIM, 0, stream>>>(nodes, W_dec, out);
}

// Round 2
// 229.455 us; speedup vs baseline: 2.1302x; 2.1302x over previous
//
#include <hip/hip_runtime.h>
#include <math.h>

#define B 2
#define N 512
#define DIM 256
#define HEADS 8
#define DHEAD 32
#define INNER 256
#define DEPTH 2
#define SCALE 0.17677669529663687f

// ---------------- encode: nodes = [x,t] @ W_enc ----------------
__global__ void k_encode(const float* __restrict__ x, const float* __restrict__ t,
                         const float* __restrict__ Wenc, float* __restrict__ nodes) {
    int bn = blockIdx.x;            // 0..B*N-1
    int d  = threadIdx.x;           // 0..255
    float x0 = x[bn*3+0], x1 = x[bn*3+1], x2 = x[bn*3+2], tt = t[bn];
    nodes[bn*DIM + d] = x0*Wenc[0*DIM+d] + x1*Wenc[1*DIM+d] + x2*Wenc[2*DIM+d] + tt*Wenc[3*DIM+d];
}

// ---------------- pairwise distances ----------------
__global__ void k_dist(const float* __restrict__ x, float* __restrict__ dist) {
    int b = blockIdx.x / N, i = blockIdx.x % N, j = threadIdx.x;  // block 512
    const float* xi = x + (b*N+i)*3;
    const float* xj = x + (b*N+j)*3;
    float d0 = xi[0]-xj[0], d1 = xi[1]-xj[1], d2 = xi[2]-xj[2];
    float s = d0*d0 + d1*d1 + d2*d2;
    dist[(size_t)(b*N+i)*N + j] = (s > 0.f) ? sqrtf(s) : 0.f;
}

// ------------- LN + QKV proj + rotary + (q.we, q.be) -------------
__global__ void k_ln_qkv(const float* __restrict__ nodes,
                         const float* __restrict__ ln_g, const float* __restrict__ ln_b,
                         const float* __restrict__ Wq, const float* __restrict__ bq,
                         const float* __restrict__ Wkv, const float* __restrict__ bkv,
                         const float* __restrict__ We, const float* __restrict__ be,
                         float* __restrict__ qbuf, float* __restrict__ kbuf, float* __restrict__ vbuf,
                         float* __restrict__ qwe, float* __restrict__ qbe, int layer) {
    __shared__ float h[DIM];
    __shared__ float red[DIM];
    __shared__ float qs[DIM], ks[DIM];
    int bn = blockIdx.x;            // b*N + i
    int d  = threadIdx.x;           // 0..255
    int b  = bn >> 9;
    int i  = bn & (N-1);

    float xv = nodes[bn*DIM + d];
    red[d] = xv; __syncthreads();
    for (int s = 128; s > 0; s >>= 1) { if (d < s) red[d] += red[d+s]; __syncthreads(); }
    float mean = red[0] * (1.0f/DIM);
    __syncthreads();
    float c = xv - mean;
    red[d] = c*c; __syncthreads();
    for (int s = 128; s > 0; s >>= 1) { if (d < s) red[d] += red[d+s]; __syncthreads(); }
    float var = red[0] * (1.0f/DIM);
    float hv = c * (1.0f/sqrtf(var + 1e-5f)) * ln_g[layer*DIM+d] + ln_b[layer*DIM+d];
    h[d] = hv;
    __syncthreads();

    const float* Wql  = Wq  + (size_t)layer*DIM*INNER;
    const float* Wkvl = Wkv + (size_t)layer*DIM*2*INNER;
    float qacc = bq[layer*INNER + d];
    float kacc = bkv[layer*2*INNER + d];
    float vacc = bkv[layer*2*INNER + INNER + d];
    #pragma unroll 4
    for (int kk = 0; kk < DIM; ++kk) {
        float hk = h[kk];
        qacc += hk * Wql [kk*INNER + d];
        kacc += hk * Wkvl[kk*2*INNER + d];
        vacc += hk * Wkvl[kk*2*INNER + INNER + d];
    }

    // rotary: head-dim index dd in [0,32); angle = i * invfreq[dd%16]
    int dd = d & 31;
    int jj = dd & 15;
    double invf = 1.0 / pow(10000.0, (double)(2*jj) / 32.0);
    double ang  = (double)i * invf;
    float ca = (float)cos(ang), sa = (float)sin(ang);

    qs[d] = qacc; ks[d] = kacc;
    __syncthreads();
    int partner = (dd < 16) ? d + 16 : d - 16;
    float sgn   = (dd < 16) ? -1.f : 1.f;
    float qrot = qacc*ca + sgn*qs[partner]*sa;
    float krot = kacc*ca + sgn*ks[partner]*sa;

    qbuf[bn*INNER + d] = qrot;
    kbuf[bn*INNER + d] = krot;
    vbuf[bn*INNER + d] = vacc;

    __syncthreads();                 // all partner reads done
    qs[d] = qrot * We[layer*INNER + d];
    ks[d] = qrot * be[layer*INNER + d];
    __syncthreads();
    if (d < HEADS) {
        float sw = 0.f, sb = 0.f;
        #pragma unroll
        for (int u = 0; u < DHEAD; ++u) { sw += qs[d*DHEAD+u]; sb += ks[d*DHEAD+u]; }
        qwe[(b*HEADS + d)*N + i] = sw;
        qbe[(b*HEADS + d)*N + i] = sb;
    }
}

// ------------- attention v2: LDS-tiled, register-blocked -------------
// block = 128 threads = (b, h, itile of 16 rows). thread t: il = t>>3 (row),
// g = t&7 (j-slice). thread owns j = jt*64 + g*8 + u (u=0..7) across 8 tiles.
#define TI 16
#define DPAD 520   // dist row pad (floats): breaks bank-conflict periodicity, 16B-aligned

__global__ __launch_bounds__(128, 2)
void k_attn(const float* __restrict__ qbuf, const float* __restrict__ kbuf,
            const float* __restrict__ vbuf,
            const float* __restrict__ qwe, const float* __restrict__ qbe,
            const float* __restrict__ dist,
            const float* __restrict__ We, const float* __restrict__ be,
            float* __restrict__ attnout, int layer) {
    __shared__ float Dsh[TI * DPAD];      // 16 dist rows, padded
    __shared__ float Tt[32 * 64];         // transposed K or V tile: [d][j]

    int t = threadIdx.x;                  // 0..127
    int g = t & 7;
    int il = t >> 3;                      // 0..15
    int bid = blockIdx.x;                 // ((b*HEADS+h)*32 + itile)
    int itile = bid & 31;
    int h = (bid >> 5) & (HEADS-1);
    int b = bid >> 8;
    int i = itile * TI + il;

    // ---- stage 16 dist rows (coalesced float4) ----
    for (int f = t; f < TI * 128; f += 128) {
        int r = f >> 7, c4 = f & 127;
        float4 v = ((const float4*)(dist + (size_t)(b*N + itile*TI + r) * N))[c4];
        *(float4*)&Dsh[r * DPAD + c4 * 4] = v;
    }

    // ---- q row into registers ----
    float q[32];
    {
        const float4* qp = (const float4*)(qbuf + (size_t)(b*N + i) * INNER + h * DHEAD);
        #pragma unroll
        for (int c = 0; c < 8; ++c) {
            float4 v = qp[c];
            q[c*4+0] = v.x; q[c*4+1] = v.y; q[c*4+2] = v.z; q[c*4+3] = v.w;
        }
    }
    float qw = qwe[(b*HEADS + h)*N + i];
    float qb = qbe[(b*HEADS + h)*N + i];

    float sim[64];

    const float* kbase = kbuf + (size_t)b*N*INNER + h*DHEAD;
    const float* vbase = vbuf + (size_t)b*N*INNER + h*DHEAD;

    // ---- QK phase ----
    for (int jt = 0; jt < 8; ++jt) {
        __syncthreads();   // Dsh ready (jt=0) / prev Tt reads done
        for (int f = t; f < 512; f += 128) {          // stage K tile transposed
            int r = f >> 3, c4 = f & 7;
            float4 v = *(const float4*)(kbase + (size_t)(jt*64 + r) * INNER + c4 * 4);
            int cc = c4 * 4;
            Tt[(cc+0)*64 + r] = v.x;
            Tt[(cc+1)*64 + r] = v.y;
            Tt[(cc+2)*64 + r] = v.z;
            Tt[(cc+3)*64 + r] = v.w;
        }
        __syncthreads();
        float4 sa = make_float4(0.f,0.f,0.f,0.f);
        float4 sb = make_float4(0.f,0.f,0.f,0.f);
        #pragma unroll
        for (int d = 0; d < 32; ++d) {
            float4 ka = *(const float4*)&Tt[d*64 + g*8];
            float4 kb = *(const float4*)&Tt[d*64 + g*8 + 4];
            float qd = q[d];
            sa.x += qd*ka.x; sa.y += qd*ka.y; sa.z += qd*ka.z; sa.w += qd*ka.w;
            sb.x += qd*kb.x; sb.y += qd*kb.y; sb.z += qd*kb.z; sb.w += qd*kb.w;
        }
        const float* drow = &Dsh[il*DPAD + jt*64 + g*8];
        float4 da = *(const float4*)&drow[0];
        float4 db = *(const float4*)&drow[4];
        sim[jt*8+0] = (sa.x + da.x*qw + qb) * SCALE;
        sim[jt*8+1] = (sa.y + da.y*qw + qb) * SCALE;
        sim[jt*8+2] = (sa.z + da.z*qw + qb) * SCALE;
        sim[jt*8+3] = (sa.w + da.w*qw + qb) * SCALE;
        sim[jt*8+4] = (sb.x + db.x*qw + qb) * SCALE;
        sim[jt*8+5] = (sb.y + db.y*qw + qb) * SCALE;
        sim[jt*8+6] = (sb.z + db.z*qw + qb) * SCALE;
        sim[jt*8+7] = (sb.w + db.w*qw + qb) * SCALE;
    }

    // ---- softmax over the row (8 lanes share a row) ----
    float mx = -1e30f;
    #pragma unroll
    for (int v = 0; v < 64; ++v) mx = fmaxf(mx, sim[v]);
    mx = fmaxf(mx, __shfl_xor(mx, 1));
    mx = fmaxf(mx, __shfl_xor(mx, 2));
    mx = fmaxf(mx, __shfl_xor(mx, 4));

    float lsum = 0.f, ldsum = 0.f;
    #pragma unroll
    for (int jt = 0; jt < 8; ++jt) {
        const float* drow = &Dsh[il*DPAD + jt*64 + g*8];
        float4 da = *(const float4*)&drow[0];
        float4 db = *(const float4*)&drow[4];
        float dv[8] = {da.x,da.y,da.z,da.w,db.x,db.y,db.z,db.w};
        #pragma unroll
        for (int u = 0; u < 8; ++u) {
            float p = __expf(sim[jt*8+u] - mx);
            sim[jt*8+u] = p;
            lsum  += p;
            ldsum += p * dv[u];
        }
    }
    lsum += __shfl_xor(lsum, 1); ldsum += __shfl_xor(ldsum, 1);
    lsum += __shfl_xor(lsum, 2); ldsum += __shfl_xor(ldsum, 2);
    lsum += __shfl_xor(lsum, 4); ldsum += __shfl_xor(ldsum, 4);

    // ---- PV phase ----
    float acc[32];
    #pragma unroll
    for (int d = 0; d < 32; ++d) acc[d] = 0.f;

    for (int jt = 0; jt < 8; ++jt) {
        __syncthreads();   // prev Tt reads done
        for (int f = t; f < 512; f += 128) {          // stage V tile transposed
            int r = f >> 3, c4 = f & 7;
            float4 v = *(const float4*)(vbase + (size_t)(jt*64 + r) * INNER + c4 * 4);
            int cc = c4 * 4;
            Tt[(cc+0)*64 + r] = v.x;
            Tt[(cc+1)*64 + r] = v.y;
            Tt[(cc+2)*64 + r] = v.z;
            Tt[(cc+3)*64 + r] = v.w;
        }
        __syncthreads();
        float p0 = sim[jt*8+0], p1 = sim[jt*8+1], p2 = sim[jt*8+2], p3 = sim[jt*8+3];
        float p4 = sim[jt*8+4], p5 = sim[jt*8+5], p6 = sim[jt*8+6], p7 = sim[jt*8+7];
        #pragma unroll
        for (int d = 0; d < 32; ++d) {
            float4 va = *(const float4*)&Tt[d*64 + g*8];
            float4 vb = *(const float4*)&Tt[d*64 + g*8 + 4];
            acc[d] += p0*va.x + p1*va.y + p2*va.z + p3*va.w
                    + p4*vb.x + p5*vb.y + p6*vb.z + p7*vb.w;
        }
    }

    // reduce acc over the 8 j-slice lanes
    #pragma unroll
    for (int d = 0; d < 32; ++d) {
        acc[d] += __shfl_xor(acc[d], 1);
        acc[d] += __shfl_xor(acc[d], 2);
        acc[d] += __shfl_xor(acc[d], 4);
    }

    float invl = 1.0f / lsum;
    float ad = ldsum * invl;
    const float* Wel = We + layer*INNER + h*DHEAD;
    const float* bel = be + layer*INNER + h*DHEAD;
    int d0 = g * 4;
    float4 o;
    o.x = acc[d0+0]*invl + ad*Wel[d0+0] + bel[d0+0];
    o.y = acc[d0+1]*invl + ad*Wel[d0+1] + bel[d0+1];
    o.z = acc[d0+2]*invl + ad*Wel[d0+2] + bel[d0+2];
    o.w = acc[d0+3]*invl + ad*Wel[d0+3] + bel[d0+3];
    *(float4*)&attnout[(size_t)(b*N + i)*INNER + h*DHEAD + d0] = o;
}

// ------------- output proj + scalar gate + residual -------------
__global__ void k_proj_gate(const float* __restrict__ attnout,
                            const float* __restrict__ Wo, const float* __restrict__ bo,
                            const float* __restrict__ Wg,
                            float* __restrict__ nodes, int layer) {
    __shared__ float a[INNER];
    __shared__ float red[DIM];
    int bn = blockIdx.x, d = threadIdx.x;
    a[d] = attnout[bn*INNER + d];
    __syncthreads();
    const float* Wol = Wo + (size_t)layer*INNER*DIM;
    float o = bo[layer*DIM + d];
    #pragma unroll 4
    for (int kk = 0; kk < INNER; ++kk) o += a[kk] * Wol[kk*DIM + d];
    float nd = nodes[bn*DIM + d];
    const float* Wgl = Wg + layer*3*DIM;
    red[d] = o*Wgl[d] + nd*Wgl[DIM+d] + (o-nd)*Wgl[2*DIM+d];
    __syncthreads();
    for (int s = 128; s > 0; s >>= 1) { if (d < s) red[d] += red[d+s]; __syncthreads(); }
    float gate = 1.0f/(1.0f + expf(-red[0]));
    nodes[bn*DIM + d] = o*gate + nd*(1.0f-gate);
}

// ---------------- decode: out = nodes @ W_dec ----------------
__global__ void k_decode(const float* __restrict__ nodes, const float* __restrict__ Wdec,
                         float* __restrict__ out) {
    __shared__ float red[3][DIM];
    int bn = blockIdx.x, d = threadIdx.x;
    float nd = nodes[bn*DIM + d];
    red[0][d] = nd * Wdec[d*3+0];
    red[1][d] = nd * Wdec[d*3+1];
    red[2][d] = nd * Wdec[d*3+2];
    __syncthreads();
    for (int s = 128; s > 0; s >>= 1) {
        if (d < s) { red[0][d]+=red[0][d+s]; red[1][d]+=red[1][d+s]; red[2][d]+=red[2][d+s]; }
        __syncthreads();
    }
    if (d < 3) out[bn*3 + d] = red[d][0];
}

extern "C" void kernel_launch(void* const* d_in, const int* in_sizes, int n_in,
                              void* d_out, int out_size, void* d_ws, size_t ws_size,
                              hipStream_t stream) {
    const float* x     = (const float*)d_in[0];
    const float* t     = (const float*)d_in[1];
    const float* W_enc = (const float*)d_in[2];
    const float* W_dec = (const float*)d_in[3];
    const float* ln_g  = (const float*)d_in[4];
    const float* ln_b  = (const float*)d_in[5];
    const float* Wq    = (const float*)d_in[6];
    const float* bq    = (const float*)d_in[7];
    const float* Wkv   = (const float*)d_in[8];
    const float* bkv   = (const float*)d_in[9];
    const float* We    = (const float*)d_in[10];
    const float* be    = (const float*)d_in[11];
    const float* Wo    = (const float*)d_in[12];
    const float* bo    = (const float*)d_in[13];
    const float* Wg    = (const float*)d_in[14];
    float* out = (float*)d_out;

    float* ws = (float*)d_ws;
    float* nodes   = ws;                       // B*N*DIM
    float* dist    = nodes   + B*N*DIM;        // B*N*N
    float* qbuf    = dist    + B*N*N;          // B*N*INNER
    float* kbuf    = qbuf    + B*N*INNER;
    float* vbuf    = kbuf    + B*N*INNER;
    float* qwe     = vbuf    + B*N*INNER;      // B*HEADS*N
    float* qbe     = qwe     + B*HEADS*N;
    float* attnout = qbe     + B*HEADS*N;      // B*N*INNER

    k_encode<<<B*N, DIM, 0, stream>>>(x, t, W_enc, nodes);
    k_dist  <<<B*N, N,   0, stream>>>(x, dist);
    for (int l = 0; l < DEPTH; ++l) {
        k_ln_qkv<<<B*N, DIM, 0, stream>>>(nodes, ln_g, ln_b, Wq, bq, Wkv, bkv, We, be,
                                          qbuf, kbuf, vbuf, qwe, qbe, l);
        k_attn<<<B*HEADS*(N/TI), 128, 0, stream>>>(qbuf, kbuf, vbuf, qwe, qbe, dist, We, be,
                                                   attnout, l);
        k_proj_gate<<<B*N, DIM, 0, stream>>>(attnout, Wo, bo, Wg, nodes, l);
    }
    k_decode<<<B*N, DIM, 0, stream>>>(nodes, W_dec, out);
}

// Round 3
// 176.285 us; speedup vs baseline: 2.7727x; 1.3016x over previous
//
#include <hip/hip_runtime.h>
#include <math.h>

#define B 2
#define N 512
#define DIM 256
#define HEADS 8
#define DHEAD 32
#define INNER 256
#define DEPTH 2
#define SCALE 0.17677669529663687f

// ---------------- encode: nodes = [x,t] @ W_enc ----------------
__global__ void k_encode(const float* __restrict__ x, const float* __restrict__ t,
                         const float* __restrict__ Wenc, float* __restrict__ nodes) {
    int bn = blockIdx.x;            // 0..B*N-1
    int d  = threadIdx.x;           // 0..255
    float x0 = x[bn*3+0], x1 = x[bn*3+1], x2 = x[bn*3+2], tt = t[bn];
    nodes[bn*DIM + d] = x0*Wenc[0*DIM+d] + x1*Wenc[1*DIM+d] + x2*Wenc[2*DIM+d] + tt*Wenc[3*DIM+d];
}

// ---------------- pairwise distances ----------------
__global__ void k_dist(const float* __restrict__ x, float* __restrict__ dist) {
    int b = blockIdx.x / N, i = blockIdx.x % N, j = threadIdx.x;  // block 512
    const float* xi = x + (b*N+i)*3;
    const float* xj = x + (b*N+j)*3;
    float d0 = xi[0]-xj[0], d1 = xi[1]-xj[1], d2 = xi[2]-xj[2];
    float s = d0*d0 + d1*d1 + d2*d2;
    dist[(size_t)(b*N+i)*N + j] = (s > 0.f) ? sqrtf(s) : 0.f;
}

// ------------- LN + QKV proj + rotary + (q.we, q.be) -------------
__global__ void k_ln_qkv(const float* __restrict__ nodes,
                         const float* __restrict__ ln_g, const float* __restrict__ ln_b,
                         const float* __restrict__ Wq, const float* __restrict__ bq,
                         const float* __restrict__ Wkv, const float* __restrict__ bkv,
                         const float* __restrict__ We, const float* __restrict__ be,
                         float* __restrict__ qbuf, float* __restrict__ kbuf, float* __restrict__ vbuf,
                         float* __restrict__ qwe, float* __restrict__ qbe, int layer) {
    __shared__ float h[DIM];
    __shared__ float red[DIM];
    __shared__ float qs[DIM], ks[DIM];
    int bn = blockIdx.x;            // b*N + i
    int d  = threadIdx.x;           // 0..255
    int b  = bn >> 9;
    int i  = bn & (N-1);

    float xv = nodes[bn*DIM + d];
    red[d] = xv; __syncthreads();
    for (int s = 128; s > 0; s >>= 1) { if (d < s) red[d] += red[d+s]; __syncthreads(); }
    float mean = red[0] * (1.0f/DIM);
    __syncthreads();
    float c = xv - mean;
    red[d] = c*c; __syncthreads();
    for (int s = 128; s > 0; s >>= 1) { if (d < s) red[d] += red[d+s]; __syncthreads(); }
    float var = red[0] * (1.0f/DIM);
    float hv = c * (1.0f/sqrtf(var + 1e-5f)) * ln_g[layer*DIM+d] + ln_b[layer*DIM+d];
    h[d] = hv;
    __syncthreads();

    const float* Wql  = Wq  + (size_t)layer*DIM*INNER;
    const float* Wkvl = Wkv + (size_t)layer*DIM*2*INNER;
    float qacc = bq[layer*INNER + d];
    float kacc = bkv[layer*2*INNER + d];
    float vacc = bkv[layer*2*INNER + INNER + d];
    #pragma unroll 4
    for (int kk = 0; kk < DIM; ++kk) {
        float hk = h[kk];
        qacc += hk * Wql [kk*INNER + d];
        kacc += hk * Wkvl[kk*2*INNER + d];
        vacc += hk * Wkvl[kk*2*INNER + INNER + d];
    }

    // rotary: head-dim index dd in [0,32); angle = i * invfreq[dd%16]
    int dd = d & 31;
    int jj = dd & 15;
    double invf = 1.0 / pow(10000.0, (double)(2*jj) / 32.0);
    double ang  = (double)i * invf;
    float ca = (float)cos(ang), sa = (float)sin(ang);

    qs[d] = qacc; ks[d] = kacc;
    __syncthreads();
    int partner = (dd < 16) ? d + 16 : d - 16;
    float sgn   = (dd < 16) ? -1.f : 1.f;
    float qrot = qacc*ca + sgn*qs[partner]*sa;
    float krot = kacc*ca + sgn*ks[partner]*sa;

    qbuf[bn*INNER + d] = qrot;
    kbuf[bn*INNER + d] = krot;
    vbuf[bn*INNER + d] = vacc;

    __syncthreads();                 // all partner reads done
    qs[d] = qrot * We[layer*INNER + d];
    ks[d] = qrot * be[layer*INNER + d];
    __syncthreads();
    if (d < HEADS) {
        float sw = 0.f, sb = 0.f;
        #pragma unroll
        for (int u = 0; u < DHEAD; ++u) { sw += qs[d*DHEAD+u]; sb += ks[d*DHEAD+u]; }
        qwe[(b*HEADS + d)*N + i] = sw;
        qbe[(b*HEADS + d)*N + i] = sb;
    }
}

// ------------- attention v3: high-occupancy, LDS-tiled -------------
// block = 256 threads = 4 waves; 8 i-rows per block (2 rows per wave).
// thread t: r = t>>5 (row 0..7), g = t&31 (j-slice). lane owns j = jt*128+g*4+{0..3}.
#define TI 8

__global__ __launch_bounds__(256, 4)
void k_attn(const float* __restrict__ qbuf, const float* __restrict__ kbuf,
            const float* __restrict__ vbuf,
            const float* __restrict__ qwe, const float* __restrict__ qbe,
            const float* __restrict__ dist,
            const float* __restrict__ We, const float* __restrict__ be,
            float* __restrict__ attnout, int layer) {
    __shared__ float Tt[32 * 128];        // transposed K or V tile: [d][j], 16KB

    int t = threadIdx.x;                  // 0..255
    int g = t & 31;
    int r = t >> 5;                       // 0..7
    int bid = blockIdx.x;                 // b*HEADS*64 + h*64 + itile
    int itile = bid & 63;
    int h = (bid >> 6) & (HEADS-1);
    int b = bid >> 9;
    int i = itile * TI + r;

    // staging coords (used for both K and V tiles)
    int scol = t & 127;                   // tile column (j within tile)
    int d0   = (t >> 7) * 16;             // d-half

    // ---- q row into registers ----
    float q[32];
    {
        const float4* qp = (const float4*)(qbuf + (size_t)(b*N + i) * INNER + h * DHEAD);
        #pragma unroll
        for (int c = 0; c < 8; ++c) {
            float4 v = qp[c];
            q[c*4+0] = v.x; q[c*4+1] = v.y; q[c*4+2] = v.z; q[c*4+3] = v.w;
        }
    }
    float qw = qwe[(b*HEADS + h)*N + i];
    float qb = qbe[(b*HEADS + h)*N + i];

    const float* kbase = kbuf + (size_t)b*N*INNER + h*DHEAD;
    const float* vbase = vbuf + (size_t)b*N*INNER + h*DHEAD;
    const float* drow  = dist + (size_t)(b*N + i) * N;

    float sim[16];

    // ---- QK phase: 4 tiles of 128 j ----
    #pragma unroll
    for (int jt = 0; jt < 4; ++jt) {
        if (jt) __syncthreads();          // prev tile reads done
        {   // stage K^T tile: [32 d][128 j]
            const float* src = kbase + (size_t)(jt*128 + scol) * INNER + d0;
            float4 a0 = *(const float4*)(src + 0);
            float4 a1 = *(const float4*)(src + 4);
            float4 a2 = *(const float4*)(src + 8);
            float4 a3 = *(const float4*)(src + 12);
            Tt[(d0+ 0)*128 + scol] = a0.x; Tt[(d0+ 1)*128 + scol] = a0.y;
            Tt[(d0+ 2)*128 + scol] = a0.z; Tt[(d0+ 3)*128 + scol] = a0.w;
            Tt[(d0+ 4)*128 + scol] = a1.x; Tt[(d0+ 5)*128 + scol] = a1.y;
            Tt[(d0+ 6)*128 + scol] = a1.z; Tt[(d0+ 7)*128 + scol] = a1.w;
            Tt[(d0+ 8)*128 + scol] = a2.x; Tt[(d0+ 9)*128 + scol] = a2.y;
            Tt[(d0+10)*128 + scol] = a2.z; Tt[(d0+11)*128 + scol] = a2.w;
            Tt[(d0+12)*128 + scol] = a3.x; Tt[(d0+13)*128 + scol] = a3.y;
            Tt[(d0+14)*128 + scol] = a3.z; Tt[(d0+15)*128 + scol] = a3.w;
        }
        __syncthreads();
        float4 s4 = make_float4(0.f,0.f,0.f,0.f);
        #pragma unroll
        for (int d = 0; d < 32; ++d) {
            float4 kv = *(const float4*)&Tt[d*128 + g*4];
            float qd = q[d];
            s4.x += qd*kv.x; s4.y += qd*kv.y; s4.z += qd*kv.z; s4.w += qd*kv.w;
        }
        float4 dv = *(const float4*)&drow[jt*128 + g*4];
        sim[jt*4+0] = (s4.x + dv.x*qw + qb) * SCALE;
        sim[jt*4+1] = (s4.y + dv.y*qw + qb) * SCALE;
        sim[jt*4+2] = (s4.z + dv.z*qw + qb) * SCALE;
        sim[jt*4+3] = (s4.w + dv.w*qw + qb) * SCALE;
    }

    // ---- softmax over the row (32 lanes share a row) ----
    float mx = -1e30f;
    #pragma unroll
    for (int v = 0; v < 16; ++v) mx = fmaxf(mx, sim[v]);
    mx = fmaxf(mx, __shfl_xor(mx, 1));
    mx = fmaxf(mx, __shfl_xor(mx, 2));
    mx = fmaxf(mx, __shfl_xor(mx, 4));
    mx = fmaxf(mx, __shfl_xor(mx, 8));
    mx = fmaxf(mx, __shfl_xor(mx, 16));

    float lsum = 0.f, ldsum = 0.f;
    #pragma unroll
    for (int jt = 0; jt < 4; ++jt) {
        float4 dv = *(const float4*)&drow[jt*128 + g*4];
        float dvv[4] = {dv.x, dv.y, dv.z, dv.w};
        #pragma unroll
        for (int u = 0; u < 4; ++u) {
            float p = __expf(sim[jt*4+u] - mx);
            sim[jt*4+u] = p;
            lsum  += p;
            ldsum += p * dvv[u];
        }
    }
    lsum += __shfl_xor(lsum, 1);  ldsum += __shfl_xor(ldsum, 1);
    lsum += __shfl_xor(lsum, 2);  ldsum += __shfl_xor(ldsum, 2);
    lsum += __shfl_xor(lsum, 4);  ldsum += __shfl_xor(ldsum, 4);
    lsum += __shfl_xor(lsum, 8);  ldsum += __shfl_xor(ldsum, 8);
    lsum += __shfl_xor(lsum, 16); ldsum += __shfl_xor(ldsum, 16);

    // ---- PV phase ----
    float acc[32];
    #pragma unroll
    for (int d = 0; d < 32; ++d) acc[d] = 0.f;

    #pragma unroll
    for (int jt = 0; jt < 4; ++jt) {
        __syncthreads();                  // prev tile reads done
        {   // stage V^T tile
            const float* src = vbase + (size_t)(jt*128 + scol) * INNER + d0;
            float4 a0 = *(const float4*)(src + 0);
            float4 a1 = *(const float4*)(src + 4);
            float4 a2 = *(const float4*)(src + 8);
            float4 a3 = *(const float4*)(src + 12);
            Tt[(d0+ 0)*128 + scol] = a0.x; Tt[(d0+ 1)*128 + scol] = a0.y;
            Tt[(d0+ 2)*128 + scol] = a0.z; Tt[(d0+ 3)*128 + scol] = a0.w;
            Tt[(d0+ 4)*128 + scol] = a1.x; Tt[(d0+ 5)*128 + scol] = a1.y;
            Tt[(d0+ 6)*128 + scol] = a1.z; Tt[(d0+ 7)*128 + scol] = a1.w;
            Tt[(d0+ 8)*128 + scol] = a2.x; Tt[(d0+ 9)*128 + scol] = a2.y;
            Tt[(d0+10)*128 + scol] = a2.z; Tt[(d0+11)*128 + scol] = a2.w;
            Tt[(d0+12)*128 + scol] = a3.x; Tt[(d0+13)*128 + scol] = a3.y;
            Tt[(d0+14)*128 + scol] = a3.z; Tt[(d0+15)*128 + scol] = a3.w;
        }
        __syncthreads();
        float p0 = sim[jt*4+0], p1 = sim[jt*4+1], p2 = sim[jt*4+2], p3 = sim[jt*4+3];
        #pragma unroll
        for (int d = 0; d < 32; ++d) {
            float4 vv = *(const float4*)&Tt[d*128 + g*4];
            acc[d] += p0*vv.x + p1*vv.y + p2*vv.z + p3*vv.w;
        }
    }

    // reduce acc over the 32 j-slice lanes (butterfly -> all lanes hold sum)
    #pragma unroll
    for (int d = 0; d < 32; ++d) {
        acc[d] += __shfl_xor(acc[d], 1);
        acc[d] += __shfl_xor(acc[d], 2);
        acc[d] += __shfl_xor(acc[d], 4);
        acc[d] += __shfl_xor(acc[d], 8);
        acc[d] += __shfl_xor(acc[d], 16);
    }

    float invl = 1.0f / lsum;
    float ad = ldsum * invl;
    float o = acc[0];
    // select acc[g] without dynamic indexing cost: unrolled pick
    #pragma unroll
    for (int d = 1; d < 32; ++d) if (g == d) o = acc[d];
    o = o * invl + ad * We[layer*INNER + h*DHEAD + g] + be[layer*INNER + h*DHEAD + g];
    attnout[(size_t)(b*N + i)*INNER + h*DHEAD + g] = o;
}

// ------------- output proj + scalar gate + residual -------------
__global__ void k_proj_gate(const float* __restrict__ attnout,
                            const float* __restrict__ Wo, const float* __restrict__ bo,
                            const float* __restrict__ Wg,
                            float* __restrict__ nodes, int layer) {
    __shared__ float a[INNER];
    __shared__ float red[DIM];
    int bn = blockIdx.x, d = threadIdx.x;
    a[d] = attnout[bn*INNER + d];
    __syncthreads();
    const float* Wol = Wo + (size_t)layer*INNER*DIM;
    float o = bo[layer*DIM + d];
    #pragma unroll 4
    for (int kk = 0; kk < INNER; ++kk) o += a[kk] * Wol[kk*DIM + d];
    float nd = nodes[bn*DIM + d];
    const float* Wgl = Wg + layer*3*DIM;
    red[d] = o*Wgl[d] + nd*Wgl[DIM+d] + (o-nd)*Wgl[2*DIM+d];
    __syncthreads();
    for (int s = 128; s > 0; s >>= 1) { if (d < s) red[d] += red[d+s]; __syncthreads(); }
    float gate = 1.0f/(1.0f + expf(-red[0]));
    nodes[bn*DIM + d] = o*gate + nd*(1.0f-gate);
}

// ---------------- decode: out = nodes @ W_dec ----------------
__global__ void k_decode(const float* __restrict__ nodes, const float* __restrict__ Wdec,
                         float* __restrict__ out) {
    __shared__ float red[3][DIM];
    int bn = blockIdx.x, d = threadIdx.x;
    float nd = nodes[bn*DIM + d];
    red[0][d] = nd * Wdec[d*3+0];
    red[1][d] = nd * Wdec[d*3+1];
    red[2][d] = nd * Wdec[d*3+2];
    __syncthreads();
    for (int s = 128; s > 0; s >>= 1) {
        if (d < s) { red[0][d]+=red[0][d+s]; red[1][d]+=red[1][d+s]; red[2][d]+=red[2][d+s]; }
        __syncthreads();
    }
    if (d < 3) out[bn*3 + d] = red[d][0];
}

extern "C" void kernel_launch(void* const* d_in, const int* in_sizes, int n_in,
                              void* d_out, int out_size, void* d_ws, size_t ws_size,
                              hipStream_t stream) {
    const float* x     = (const float*)d_in[0];
    const float* t     = (const float*)d_in[1];
    const float* W_enc = (const float*)d_in[2];
    const float* W_dec = (const float*)d_in[3];
    const float* ln_g  = (const float*)d_in[4];
    const float* ln_b  = (const float*)d_in[5];
    const float* Wq    = (const float*)d_in[6];
    const float* bq    = (const float*)d_in[7];
    const float* Wkv   = (const float*)d_in[8];
    const float* bkv   = (const float*)d_in[9];
    const float* We    = (const float*)d_in[10];
    const float* be    = (const float*)d_in[11];
    const float* Wo    = (const float*)d_in[12];
    const float* bo    = (const float*)d_in[13];
    const float* Wg    = (const float*)d_in[14];
    float* out = (float*)d_out;

    float* ws = (float*)d_ws;
    float* nodes   = ws;                       // B*N*DIM
    float* dist    = nodes   + B*N*DIM;        // B*N*N
    float* qbuf    = dist    + B*N*N;          // B*N*INNER
    float* kbuf    = qbuf    + B*N*INNER;
    float* vbuf    = kbuf    + B*N*INNER;
    float* qwe     = vbuf    + B*N*INNER;      // B*HEADS*N
    float* qbe     = qwe     + B*HEADS*N;
    float* attnout = qbe     + B*HEADS*N;      // B*N*INNER

    k_encode<<<B*N, DIM, 0, stream>>>(x, t, W_enc, nodes);
    k_dist  <<<B*N, N,   0, stream>>>(x, dist);
    for (int l = 0; l < DEPTH; ++l) {
        k_ln_qkv<<<B*N, DIM, 0, stream>>>(nodes, ln_g, ln_b, Wq, bq, Wkv, bkv, We, be,
                                          qbuf, kbuf, vbuf, qwe, qbe, l);
        k_attn<<<B*HEADS*(N/TI), 256, 0, stream>>>(qbuf, kbuf, vbuf, qwe, qbe, dist, We, be,
                                                   attnout, l);
        k_proj_gate<<<B*N, DIM, 0, stream>>>(attnout, Wo, bo, Wg, nodes, l);
    }
    k_decode<<<B*N, DIM, 0, stream>>>(nodes, W_dec, out);
}

// Round 4
// 129.623 us; speedup vs baseline: 3.7708x; 1.3600x over previous
//
#include <hip/hip_runtime.h>
#include <math.h>

#define B 2
#define N 512
#define DIM 256
#define HEADS 8
#define DHEAD 32
#define INNER 256
#define DEPTH 2
#define SCALE 0.17677669529663687f

// ---- block-wide sum over 256 threads (4 waves), result broadcast to all ----
__device__ __forceinline__ float block_sum256(float v, float* red4) {
    #pragma unroll
    for (int o = 32; o; o >>= 1) v += __shfl_xor(v, o);
    int tid = threadIdx.x;
    __syncthreads();                       // protect prior reads of red4
    if ((tid & 63) == 0) red4[tid >> 6] = v;
    __syncthreads();
    return red4[0] + red4[1] + red4[2] + red4[3];
}

// ---------------- rotary tables: ct/st[i*16+jj] ----------------
__global__ void k_tables(float* __restrict__ ct, float* __restrict__ st) {
    int idx = blockIdx.x * 256 + threadIdx.x;      // 0..8191
    int i = idx >> 4, jj = idx & 15;
    double invf = pow(10000.0, -(double)jj / 16.0);
    double ang = (double)i * invf;
    ct[idx] = (float)cos(ang);
    st[idx] = (float)sin(ang);
}

// ---------------- encode + LN(layer0) ----------------
__global__ void k_encode_ln(const float* __restrict__ x, const float* __restrict__ t,
                            const float* __restrict__ Wenc,
                            const float* __restrict__ ln_g, const float* __restrict__ ln_b,
                            float* __restrict__ nodes, float* __restrict__ hbuf) {
    __shared__ float red4[4];
    int row = blockIdx.x, d = threadIdx.x;
    float x0 = x[row*3+0], x1 = x[row*3+1], x2 = x[row*3+2], tt = t[row];
    float nv = x0*Wenc[d] + x1*Wenc[DIM+d] + x2*Wenc[2*DIM+d] + tt*Wenc[3*DIM+d];
    nodes[row*DIM + d] = nv;
    float mean = block_sum256(nv, red4) * (1.0f/DIM);
    float c = nv - mean;
    float var = block_sum256(c*c, red4) * (1.0f/DIM);
    hbuf[row*DIM + d] = c * (1.0f/sqrtf(var + 1e-5f)) * ln_g[d] + ln_b[d];
}

// ---------------- pairwise distances ----------------
__global__ void k_dist(const float* __restrict__ x, float* __restrict__ dist) {
    int b = blockIdx.x / N, i = blockIdx.x % N, j = threadIdx.x;
    const float* xi = x + (b*N+i)*3;
    const float* xj = x + (b*N+j)*3;
    float d0 = xi[0]-xj[0], d1 = xi[1]-xj[1], d2 = xi[2]-xj[2];
    float s = d0*d0 + d1*d1 + d2*d2;
    dist[(size_t)(b*N+i)*N + j] = (s > 0.f) ? sqrtf(s) : 0.f;
}

// ------------- QKV GEMM + rotary + qwe/qbe epilogue -------------
// C[1024 x 768] = hbuf[1024 x 256] @ [Wq | Wkv], BM=32 BN=64 BK=64,
// 256 threads, micro 2x4. grid = 32 Mtiles * 12 Ntiles = 384.
__global__ __launch_bounds__(256, 4)
void k_gemm_qkv(const float* __restrict__ hbuf,
                const float* __restrict__ Wq, const float* __restrict__ bq,
                const float* __restrict__ Wkv, const float* __restrict__ bkv,
                const float* __restrict__ We, const float* __restrict__ be,
                const float* __restrict__ ct, const float* __restrict__ st,
                float* __restrict__ qbuf, float* __restrict__ kbuf, float* __restrict__ vbuf,
                float* __restrict__ qwe, float* __restrict__ qbe, int layer) {
    __shared__ float AT[64][32];       // A^T tile, 8 KB
    __shared__ float Bs[64][64];       // B tile, 16 KB (reused as rotary scratch)

    int tid = threadIdx.x;
    int mt = blockIdx.x & 31;
    int nt = blockIdx.x >> 5;          // 0..11
    int tx = tid & 15, ty = tid >> 4;
    int n0 = nt * 64;

    const float* Wsrc; int wstride;
    if (n0 < 256) { Wsrc = Wq  + (size_t)layer*256*256 + n0;        wstride = 256; }
    else          { Wsrc = Wkv + (size_t)layer*256*512 + (n0-256);  wstride = 512; }

    float acc[2][4] = {{0,0,0,0},{0,0,0,0}};

    int am = tid & 31, ak = tid >> 5;      // A loader
    int bn4 = tid & 15, bk = tid >> 4;     // B loader

    for (int kt = 0; kt < 4; ++kt) {
        int kbase = kt * 64;
        if (kt) __syncthreads();
        {   // A: hbuf rows mt*32+am, k chunk ak*8..+7
            const float* src = hbuf + (size_t)(mt*32 + am)*256 + kbase + ak*8;
            float4 a0 = *(const float4*)src;
            float4 a1 = *(const float4*)(src + 4);
            AT[ak*8+0][am]=a0.x; AT[ak*8+1][am]=a0.y; AT[ak*8+2][am]=a0.z; AT[ak*8+3][am]=a0.w;
            AT[ak*8+4][am]=a1.x; AT[ak*8+5][am]=a1.y; AT[ak*8+6][am]=a1.z; AT[ak*8+7][am]=a1.w;
        }
        #pragma unroll
        for (int p = 0; p < 4; ++p) {   // B: rows k=bk+16p
            int k = bk + p*16;
            float4 v = *(const float4*)(Wsrc + (size_t)(kbase + k)*wstride + bn4*4);
            *(float4*)&Bs[k][bn4*4] = v;
        }
        __syncthreads();
        #pragma unroll 8
        for (int k = 0; k < 64; ++k) {
            float2 a = *(const float2*)&AT[k][ty*2];
            float4 b = *(const float4*)&Bs[k][tx*4];
            acc[0][0] += a.x*b.x; acc[0][1] += a.x*b.y; acc[0][2] += a.x*b.z; acc[0][3] += a.x*b.w;
            acc[1][0] += a.y*b.x; acc[1][1] += a.y*b.y; acc[1][2] += a.y*b.z; acc[1][3] += a.y*b.w;
        }
    }

    int row = mt*32 + ty*2;
    int n = n0 + tx*4;

    // bias
    float4 bias4;
    if (n0 < 256) bias4 = *(const float4*)&bq[layer*256 + n];
    else          bias4 = *(const float4*)&bkv[layer*512 + (n - 256)];
    #pragma unroll
    for (int r = 0; r < 2; ++r) {
        acc[r][0] += bias4.x; acc[r][1] += bias4.y; acc[r][2] += bias4.z; acc[r][3] += bias4.w;
    }

    if (n0 >= 512) {                   // V tile: plain store
        #pragma unroll
        for (int r = 0; r < 2; ++r) {
            float4 o = make_float4(acc[r][0], acc[r][1], acc[r][2], acc[r][3]);
            *(float4*)&vbuf[(size_t)(row + r)*256 + (n - 512)] = o;
        }
        return;
    }

    // ---- rotary (q and k tiles): partner exchange via LDS scratch ----
    float* sh = &Bs[0][0];             // [32][68] scratch
    __syncthreads();                   // all Bs reads done
    #pragma unroll
    for (int r = 0; r < 2; ++r)
        #pragma unroll
        for (int c = 0; c < 4; ++c)
            sh[(ty*2 + r)*68 + tx*4 + c] = acc[r][c];
    __syncthreads();

    float wep[2] = {0.f, 0.f}, bep[2] = {0.f, 0.f};
    float val[2][4];
    #pragma unroll
    for (int r = 0; r < 2; ++r) {
        int ii = (row + r) & (N-1);
        #pragma unroll
        for (int c = 0; c < 4; ++c) {
            int tc = tx*4 + c;
            int dd = tc & 31, jj = tc & 15;
            float ca = ct[ii*16 + jj], sa = st[ii*16 + jj];
            int ptc = (dd < 16) ? tc + 16 : tc - 16;
            float sgn = (dd < 16) ? -1.f : 1.f;
            float partner = sh[(ty*2 + r)*68 + ptc];
            float rot = acc[r][c]*ca + sgn*partner*sa;
            val[r][c] = rot;
            if (n0 < 256) {
                wep[r] += rot * We[layer*256 + n0 + tc];
                bep[r] += rot * be[layer*256 + n0 + tc];
            }
        }
    }

    float* dst = (n0 < 256) ? qbuf : kbuf;
    int coln = (n0 < 256) ? n : n - 256;
    #pragma unroll
    for (int r = 0; r < 2; ++r) {
        float4 o = make_float4(val[r][0], val[r][1], val[r][2], val[r][3]);
        *(float4*)&dst[(size_t)(row + r)*256 + coln] = o;
    }

    if (n0 < 256) {                    // qwe/qbe: reduce over tx octet
        #pragma unroll
        for (int r = 0; r < 2; ++r) {
            wep[r] += __shfl_xor(wep[r], 1); bep[r] += __shfl_xor(bep[r], 1);
            wep[r] += __shfl_xor(wep[r], 2); bep[r] += __shfl_xor(bep[r], 2);
            wep[r] += __shfl_xor(wep[r], 4); bep[r] += __shfl_xor(bep[r], 4);
        }
        if ((tid & 7) == 0) {
            int h = nt*2 + (tx >> 3);
            int bb = row >> 9;
            #pragma unroll
            for (int r = 0; r < 2; ++r) {
                int ii = (row + r) & (N-1);
                qwe[(bb*HEADS + h)*N + ii] = wep[r];
                qbe[(bb*HEADS + h)*N + ii] = bep[r];
            }
        }
    }
}

// ------------- attention (unchanged from R2) -------------
#define TI 8
__global__ __launch_bounds__(256, 4)
void k_attn(const float* __restrict__ qbuf, const float* __restrict__ kbuf,
            const float* __restrict__ vbuf,
            const float* __restrict__ qwe, const float* __restrict__ qbe,
            const float* __restrict__ dist,
            const float* __restrict__ We, const float* __restrict__ be,
            float* __restrict__ attnout, int layer) {
    __shared__ float Tt[32 * 128];

    int t = threadIdx.x;
    int g = t & 31;
    int r = t >> 5;
    int bid = blockIdx.x;
    int itile = bid & 63;
    int h = (bid >> 6) & (HEADS-1);
    int b = bid >> 9;
    int i = itile * TI + r;

    int scol = t & 127;
    int d0   = (t >> 7) * 16;

    float q[32];
    {
        const float4* qp = (const float4*)(qbuf + (size_t)(b*N + i) * INNER + h * DHEAD);
        #pragma unroll
        for (int c = 0; c < 8; ++c) {
            float4 v = qp[c];
            q[c*4+0] = v.x; q[c*4+1] = v.y; q[c*4+2] = v.z; q[c*4+3] = v.w;
        }
    }
    float qw = qwe[(b*HEADS + h)*N + i];
    float qb = qbe[(b*HEADS + h)*N + i];

    const float* kbase = kbuf + (size_t)b*N*INNER + h*DHEAD;
    const float* vbase = vbuf + (size_t)b*N*INNER + h*DHEAD;
    const float* drow  = dist + (size_t)(b*N + i) * N;

    float sim[16];

    #pragma unroll
    for (int jt = 0; jt < 4; ++jt) {
        if (jt) __syncthreads();
        {
            const float* src = kbase + (size_t)(jt*128 + scol) * INNER + d0;
            float4 a0 = *(const float4*)(src + 0);
            float4 a1 = *(const float4*)(src + 4);
            float4 a2 = *(const float4*)(src + 8);
            float4 a3 = *(const float4*)(src + 12);
            Tt[(d0+ 0)*128 + scol] = a0.x; Tt[(d0+ 1)*128 + scol] = a0.y;
            Tt[(d0+ 2)*128 + scol] = a0.z; Tt[(d0+ 3)*128 + scol] = a0.w;
            Tt[(d0+ 4)*128 + scol] = a1.x; Tt[(d0+ 5)*128 + scol] = a1.y;
            Tt[(d0+ 6)*128 + scol] = a1.z; Tt[(d0+ 7)*128 + scol] = a1.w;
            Tt[(d0+ 8)*128 + scol] = a2.x; Tt[(d0+ 9)*128 + scol] = a2.y;
            Tt[(d0+10)*128 + scol] = a2.z; Tt[(d0+11)*128 + scol] = a2.w;
            Tt[(d0+12)*128 + scol] = a3.x; Tt[(d0+13)*128 + scol] = a3.y;
            Tt[(d0+14)*128 + scol] = a3.z; Tt[(d0+15)*128 + scol] = a3.w;
        }
        __syncthreads();
        float4 s4 = make_float4(0.f,0.f,0.f,0.f);
        #pragma unroll
        for (int d = 0; d < 32; ++d) {
            float4 kv = *(const float4*)&Tt[d*128 + g*4];
            float qd = q[d];
            s4.x += qd*kv.x; s4.y += qd*kv.y; s4.z += qd*kv.z; s4.w += qd*kv.w;
        }
        float4 dv = *(const float4*)&drow[jt*128 + g*4];
        sim[jt*4+0] = (s4.x + dv.x*qw + qb) * SCALE;
        sim[jt*4+1] = (s4.y + dv.y*qw + qb) * SCALE;
        sim[jt*4+2] = (s4.z + dv.z*qw + qb) * SCALE;
        sim[jt*4+3] = (s4.w + dv.w*qw + qb) * SCALE;
    }

    float mx = -1e30f;
    #pragma unroll
    for (int v = 0; v < 16; ++v) mx = fmaxf(mx, sim[v]);
    mx = fmaxf(mx, __shfl_xor(mx, 1));
    mx = fmaxf(mx, __shfl_xor(mx, 2));
    mx = fmaxf(mx, __shfl_xor(mx, 4));
    mx = fmaxf(mx, __shfl_xor(mx, 8));
    mx = fmaxf(mx, __shfl_xor(mx, 16));

    float lsum = 0.f, ldsum = 0.f;
    #pragma unroll
    for (int jt = 0; jt < 4; ++jt) {
        float4 dv = *(const float4*)&drow[jt*128 + g*4];
        float dvv[4] = {dv.x, dv.y, dv.z, dv.w};
        #pragma unroll
        for (int u = 0; u < 4; ++u) {
            float p = __expf(sim[jt*4+u] - mx);
            sim[jt*4+u] = p;
            lsum  += p;
            ldsum += p * dvv[u];
        }
    }
    lsum += __shfl_xor(lsum, 1);  ldsum += __shfl_xor(ldsum, 1);
    lsum += __shfl_xor(lsum, 2);  ldsum += __shfl_xor(ldsum, 2);
    lsum += __shfl_xor(lsum, 4);  ldsum += __shfl_xor(ldsum, 4);
    lsum += __shfl_xor(lsum, 8);  ldsum += __shfl_xor(ldsum, 8);
    lsum += __shfl_xor(lsum, 16); ldsum += __shfl_xor(ldsum, 16);

    float acc[32];
    #pragma unroll
    for (int d = 0; d < 32; ++d) acc[d] = 0.f;

    #pragma unroll
    for (int jt = 0; jt < 4; ++jt) {
        __syncthreads();
        {
            const float* src = vbase + (size_t)(jt*128 + scol) * INNER + d0;
            float4 a0 = *(const float4*)(src + 0);
            float4 a1 = *(const float4*)(src + 4);
            float4 a2 = *(const float4*)(src + 8);
            float4 a3 = *(const float4*)(src + 12);
            Tt[(d0+ 0)*128 + scol] = a0.x; Tt[(d0+ 1)*128 + scol] = a0.y;
            Tt[(d0+ 2)*128 + scol] = a0.z; Tt[(d0+ 3)*128 + scol] = a0.w;
            Tt[(d0+ 4)*128 + scol] = a1.x; Tt[(d0+ 5)*128 + scol] = a1.y;
            Tt[(d0+ 6)*128 + scol] = a1.z; Tt[(d0+ 7)*128 + scol] = a1.w;
            Tt[(d0+ 8)*128 + scol] = a2.x; Tt[(d0+ 9)*128 + scol] = a2.y;
            Tt[(d0+10)*128 + scol] = a2.z; Tt[(d0+11)*128 + scol] = a2.w;
            Tt[(d0+12)*128 + scol] = a3.x; Tt[(d0+13)*128 + scol] = a3.y;
            Tt[(d0+14)*128 + scol] = a3.z; Tt[(d0+15)*128 + scol] = a3.w;
        }
        __syncthreads();
        float p0 = sim[jt*4+0], p1 = sim[jt*4+1], p2 = sim[jt*4+2], p3 = sim[jt*4+3];
        #pragma unroll
        for (int d = 0; d < 32; ++d) {
            float4 vv = *(const float4*)&Tt[d*128 + g*4];
            acc[d] += p0*vv.x + p1*vv.y + p2*vv.z + p3*vv.w;
        }
    }

    #pragma unroll
    for (int d = 0; d < 32; ++d) {
        acc[d] += __shfl_xor(acc[d], 1);
        acc[d] += __shfl_xor(acc[d], 2);
        acc[d] += __shfl_xor(acc[d], 4);
        acc[d] += __shfl_xor(acc[d], 8);
        acc[d] += __shfl_xor(acc[d], 16);
    }

    float invl = 1.0f / lsum;
    float ad = ldsum * invl;
    float o = acc[0];
    #pragma unroll
    for (int d = 1; d < 32; ++d) if (g == d) o = acc[d];
    o = o * invl + ad * We[layer*INNER + h*DHEAD + g] + be[layer*INNER + h*DHEAD + g];
    attnout[(size_t)(b*N + i)*INNER + h*DHEAD + g] = o;
}

// ------------- O GEMM: obuf = attnout @ Wo + bo -------------
// BM=32 BN=32 BK=64, 256 threads, micro 1x4. grid = 32*8 = 256.
__global__ __launch_bounds__(256, 4)
void k_gemm_o(const float* __restrict__ attnout, const float* __restrict__ Wo,
              const float* __restrict__ bo, float* __restrict__ obuf, int layer) {
    __shared__ float AT[64][32];
    __shared__ float Bs[64][32];
    int tid = threadIdx.x;
    int mt = blockIdx.x & 31, nt = blockIdx.x >> 5;
    int tx = tid & 7, ty = tid >> 3;

    float acc[4] = {0,0,0,0};
    int am = tid & 31, ak = tid >> 5;
    int bn4 = tid & 7, bk = tid >> 3;
    const float* Wsrc = Wo + (size_t)layer*256*256 + nt*32;

    for (int kt = 0; kt < 4; ++kt) {
        int kbase = kt * 64;
        if (kt) __syncthreads();
        {
            const float* src = attnout + (size_t)(mt*32 + am)*256 + kbase + ak*8;
            float4 a0 = *(const float4*)src;
            float4 a1 = *(const float4*)(src + 4);
            AT[ak*8+0][am]=a0.x; AT[ak*8+1][am]=a0.y; AT[ak*8+2][am]=a0.z; AT[ak*8+3][am]=a0.w;
            AT[ak*8+4][am]=a1.x; AT[ak*8+5][am]=a1.y; AT[ak*8+6][am]=a1.z; AT[ak*8+7][am]=a1.w;
        }
        #pragma unroll
        for (int p = 0; p < 2; ++p) {
            int k = bk + p*32;
            *(float4*)&Bs[k][bn4*4] = *(const float4*)(Wsrc + (size_t)(kbase + k)*256 + bn4*4);
        }
        __syncthreads();
        #pragma unroll 8
        for (int k = 0; k < 64; ++k) {
            float a = AT[k][ty];
            float4 b = *(const float4*)&Bs[k][tx*4];
            acc[0] += a*b.x; acc[1] += a*b.y; acc[2] += a*b.z; acc[3] += a*b.w;
        }
    }
    int row = mt*32 + ty, n = nt*32 + tx*4;
    float4 bias = *(const float4*)&bo[layer*256 + n];
    float4 o = make_float4(acc[0]+bias.x, acc[1]+bias.y, acc[2]+bias.z, acc[3]+bias.w);
    *(float4*)&obuf[(size_t)row*256 + n] = o;
}

// ------------- gate + residual, then LN(next) or decode -------------
__global__ void k_gate_ln(const float* __restrict__ obuf, const float* __restrict__ Wg,
                          const float* __restrict__ ln_g, const float* __restrict__ ln_b,
                          const float* __restrict__ Wdec,
                          float* __restrict__ nodes, float* __restrict__ hbuf,
                          float* __restrict__ out, int layer) {
    __shared__ float red4[4];
    int row = blockIdx.x, d = threadIdx.x;
    float o  = obuf[row*DIM + d];
    float nd = nodes[row*DIM + d];
    const float* Wgl = Wg + layer*3*DIM;
    float s = o*Wgl[d] + nd*Wgl[DIM+d] + (o-nd)*Wgl[2*DIM+d];
    float tot = block_sum256(s, red4);
    float gate = 1.0f/(1.0f + __expf(-tot));
    float nn = o*gate + nd*(1.0f - gate);
    nodes[row*DIM + d] = nn;
    if (layer == 0) {
        float mean = block_sum256(nn, red4) * (1.0f/DIM);
        float c = nn - mean;
        float var = block_sum256(c*c, red4) * (1.0f/DIM);
        hbuf[row*DIM + d] = c * (1.0f/sqrtf(var + 1e-5f)) * ln_g[DIM + d] + ln_b[DIM + d];
    } else {
        float s0 = block_sum256(nn * Wdec[d*3+0], red4);
        float s1 = block_sum256(nn * Wdec[d*3+1], red4);
        float s2 = block_sum256(nn * Wdec[d*3+2], red4);
        if (d == 0) { out[row*3+0] = s0; out[row*3+1] = s1; out[row*3+2] = s2; }
    }
}

extern "C" void kernel_launch(void* const* d_in, const int* in_sizes, int n_in,
                              void* d_out, int out_size, void* d_ws, size_t ws_size,
                              hipStream_t stream) {
    const float* x     = (const float*)d_in[0];
    const float* t     = (const float*)d_in[1];
    const float* W_enc = (const float*)d_in[2];
    const float* W_dec = (const float*)d_in[3];
    const float* ln_g  = (const float*)d_in[4];
    const float* ln_b  = (const float*)d_in[5];
    const float* Wq    = (const float*)d_in[6];
    const float* bq    = (const float*)d_in[7];
    const float* Wkv   = (const float*)d_in[8];
    const float* bkv   = (const float*)d_in[9];
    const float* We    = (const float*)d_in[10];
    const float* be    = (const float*)d_in[11];
    const float* Wo    = (const float*)d_in[12];
    const float* bo    = (const float*)d_in[13];
    const float* Wg    = (const float*)d_in[14];
    float* out = (float*)d_out;

    float* ws = (float*)d_ws;
    float* nodes   = ws;                       // 262144
    float* dist    = nodes   + B*N*DIM;        // 524288
    float* hbuf    = dist    + B*N*N;          // 262144
    float* qbuf    = hbuf    + B*N*DIM;        // 262144
    float* kbuf    = qbuf    + B*N*INNER;
    float* vbuf    = kbuf    + B*N*INNER;
    float* qwe     = vbuf    + B*N*INNER;      // 8192
    float* qbe     = qwe     + B*HEADS*N;
    float* attnout = qbe     + B*HEADS*N;      // 262144
    float* obuf    = attnout + B*N*INNER;      // 262144
    float* ct      = obuf    + B*N*DIM;        // 8192
    float* st      = ct      + N*16;

    k_tables   <<<32,   256, 0, stream>>>(ct, st);
    k_encode_ln<<<B*N,  DIM, 0, stream>>>(x, t, W_enc, ln_g, ln_b, nodes, hbuf);
    k_dist     <<<B*N,  N,   0, stream>>>(x, dist);
    for (int l = 0; l < DEPTH; ++l) {
        k_gemm_qkv<<<384, 256, 0, stream>>>(hbuf, Wq, bq, Wkv, bkv, We, be, ct, st,
                                            qbuf, kbuf, vbuf, qwe, qbe, l);
        k_attn<<<B*HEADS*(N/TI), 256, 0, stream>>>(qbuf, kbuf, vbuf, qwe, qbe, dist, We, be,
                                                   attnout, l);
        k_gemm_o<<<256, 256, 0, stream>>>(attnout, Wo, bo, obuf, l);
        k_gate_ln<<<B*N, DIM, 0, stream>>>(obuf, Wg, ln_g, ln_b, W_dec, nodes, hbuf, out, l);
    }
}

// Round 5
// 112.897 us; speedup vs baseline: 4.3295x; 1.1482x over previous
//
#include <hip/hip_runtime.h>
#include <math.h>

#define B 2
#define N 512
#define DIM 256
#define HEADS 8
#define DHEAD 32
#define INNER 256
#define DEPTH 2
#define SCALE 0.17677669529663687f

// ---- block-wide sum over 256 threads (4 waves), result broadcast to all ----
__device__ __forceinline__ float block_sum256(float v, float* red4) {
    #pragma unroll
    for (int o = 32; o; o >>= 1) v += __shfl_xor(v, o);
    int tid = threadIdx.x;
    __syncthreads();                       // protect prior reads of red4
    if ((tid & 63) == 0) red4[tid >> 6] = v;
    __syncthreads();
    return red4[0] + red4[1] + red4[2] + red4[3];
}

// ------- fused: rotary tables (blocks 0..31) + encode + LN0 + dist -------
__global__ void k_pre(const float* __restrict__ x, const float* __restrict__ t,
                      const float* __restrict__ Wenc,
                      const float* __restrict__ ln_g, const float* __restrict__ ln_b,
                      float* __restrict__ nodes, float* __restrict__ hbuf,
                      float* __restrict__ dist,
                      float* __restrict__ ct, float* __restrict__ st) {
    __shared__ float red4[4];
    __shared__ float xs[N * 3];
    int row = blockIdx.x, d = threadIdx.x;
    int b = row >> 9, i = row & (N - 1);

    if (blockIdx.x < 32) {                 // rotary tables: 8192 entries
        int idx = blockIdx.x * 256 + d;
        int ii = idx >> 4, jj = idx & 15;
        double invf = pow(10000.0, -(double)jj / 16.0);
        double ang = (double)ii * invf;
        ct[idx] = (float)cos(ang);
        st[idx] = (float)sin(ang);
    }

    // encode + LN(layer 0)
    float x0 = x[row*3+0], x1 = x[row*3+1], x2 = x[row*3+2], tt = t[row];
    float nv = x0*Wenc[d] + x1*Wenc[DIM+d] + x2*Wenc[2*DIM+d] + tt*Wenc[3*DIM+d];
    nodes[row*DIM + d] = nv;
    float mean = block_sum256(nv, red4) * (1.0f/DIM);
    float c = nv - mean;
    float var = block_sum256(c*c, red4) * (1.0f/DIM);
    hbuf[row*DIM + d] = c * (1.0f/sqrtf(var + 1e-5f)) * ln_g[d] + ln_b[d];

    // dist row i vs all j (x[b] staged in LDS)
    for (int f = d; f < N*3; f += 256) xs[f] = x[b*N*3 + f];
    __syncthreads();
    float xi0 = xs[i*3+0], xi1 = xs[i*3+1], xi2 = xs[i*3+2];
    for (int j = d; j < N; j += 256) {
        float d0 = xi0 - xs[j*3+0], d1 = xi1 - xs[j*3+1], d2 = xi2 - xs[j*3+2];
        float s = d0*d0 + d1*d1 + d2*d2;
        dist[(size_t)row*N + j] = (s > 0.f) ? sqrtf(s) : 0.f;
    }
}

// ------------- QKV GEMM + rotary + qwe/qbe epilogue -------------
__global__ __launch_bounds__(256, 4)
void k_gemm_qkv(const float* __restrict__ hbuf,
                const float* __restrict__ Wq, const float* __restrict__ bq,
                const float* __restrict__ Wkv, const float* __restrict__ bkv,
                const float* __restrict__ We, const float* __restrict__ be,
                const float* __restrict__ ct, const float* __restrict__ st,
                float* __restrict__ qbuf, float* __restrict__ kbuf, float* __restrict__ vbuf,
                float* __restrict__ qwe, float* __restrict__ qbe, int layer) {
    __shared__ float AT[64][32];
    __shared__ float Bs[64][64];

    int tid = threadIdx.x;
    int mt = blockIdx.x & 31;
    int nt = blockIdx.x >> 5;
    int tx = tid & 15, ty = tid >> 4;
    int n0 = nt * 64;

    const float* Wsrc; int wstride;
    if (n0 < 256) { Wsrc = Wq  + (size_t)layer*256*256 + n0;        wstride = 256; }
    else          { Wsrc = Wkv + (size_t)layer*256*512 + (n0-256);  wstride = 512; }

    float acc[2][4] = {{0,0,0,0},{0,0,0,0}};

    int am = tid & 31, ak = tid >> 5;
    int bn4 = tid & 15, bk = tid >> 4;

    for (int kt = 0; kt < 4; ++kt) {
        int kbase = kt * 64;
        if (kt) __syncthreads();
        {
            const float* src = hbuf + (size_t)(mt*32 + am)*256 + kbase + ak*8;
            float4 a0 = *(const float4*)src;
            float4 a1 = *(const float4*)(src + 4);
            AT[ak*8+0][am]=a0.x; AT[ak*8+1][am]=a0.y; AT[ak*8+2][am]=a0.z; AT[ak*8+3][am]=a0.w;
            AT[ak*8+4][am]=a1.x; AT[ak*8+5][am]=a1.y; AT[ak*8+6][am]=a1.z; AT[ak*8+7][am]=a1.w;
        }
        #pragma unroll
        for (int p = 0; p < 4; ++p) {
            int k = bk + p*16;
            float4 v = *(const float4*)(Wsrc + (size_t)(kbase + k)*wstride + bn4*4);
            *(float4*)&Bs[k][bn4*4] = v;
        }
        __syncthreads();
        #pragma unroll 8
        for (int k = 0; k < 64; ++k) {
            float2 a = *(const float2*)&AT[k][ty*2];
            float4 b = *(const float4*)&Bs[k][tx*4];
            acc[0][0] += a.x*b.x; acc[0][1] += a.x*b.y; acc[0][2] += a.x*b.z; acc[0][3] += a.x*b.w;
            acc[1][0] += a.y*b.x; acc[1][1] += a.y*b.y; acc[1][2] += a.y*b.z; acc[1][3] += a.y*b.w;
        }
    }

    int row = mt*32 + ty*2;
    int n = n0 + tx*4;

    float4 bias4;
    if (n0 < 256) bias4 = *(const float4*)&bq[layer*256 + n];
    else          bias4 = *(const float4*)&bkv[layer*512 + (n - 256)];
    #pragma unroll
    for (int r = 0; r < 2; ++r) {
        acc[r][0] += bias4.x; acc[r][1] += bias4.y; acc[r][2] += bias4.z; acc[r][3] += bias4.w;
    }

    if (n0 >= 512) {
        #pragma unroll
        for (int r = 0; r < 2; ++r) {
            float4 o = make_float4(acc[r][0], acc[r][1], acc[r][2], acc[r][3]);
            *(float4*)&vbuf[(size_t)(row + r)*256 + (n - 512)] = o;
        }
        return;
    }

    float* sh = &Bs[0][0];
    __syncthreads();
    #pragma unroll
    for (int r = 0; r < 2; ++r)
        #pragma unroll
        for (int c = 0; c < 4; ++c)
            sh[(ty*2 + r)*68 + tx*4 + c] = acc[r][c];
    __syncthreads();

    float wep[2] = {0.f, 0.f}, bep[2] = {0.f, 0.f};
    float val[2][4];
    #pragma unroll
    for (int r = 0; r < 2; ++r) {
        int ii = (row + r) & (N-1);
        #pragma unroll
        for (int c = 0; c < 4; ++c) {
            int tc = tx*4 + c;
            int dd = tc & 31, jj = tc & 15;
            float ca = ct[ii*16 + jj], sa = st[ii*16 + jj];
            int ptc = (dd < 16) ? tc + 16 : tc - 16;
            float sgn = (dd < 16) ? -1.f : 1.f;
            float partner = sh[(ty*2 + r)*68 + ptc];
            float rot = acc[r][c]*ca + sgn*partner*sa;
            val[r][c] = rot;
            if (n0 < 256) {
                wep[r] += rot * We[layer*256 + n0 + tc];
                bep[r] += rot * be[layer*256 + n0 + tc];
            }
        }
    }

    float* dst = (n0 < 256) ? qbuf : kbuf;
    int coln = (n0 < 256) ? n : n - 256;
    #pragma unroll
    for (int r = 0; r < 2; ++r) {
        float4 o = make_float4(val[r][0], val[r][1], val[r][2], val[r][3]);
        *(float4*)&dst[(size_t)(row + r)*256 + coln] = o;
    }

    if (n0 < 256) {
        #pragma unroll
        for (int r = 0; r < 2; ++r) {
            wep[r] += __shfl_xor(wep[r], 1); bep[r] += __shfl_xor(bep[r], 1);
            wep[r] += __shfl_xor(wep[r], 2); bep[r] += __shfl_xor(bep[r], 2);
            wep[r] += __shfl_xor(wep[r], 4); bep[r] += __shfl_xor(bep[r], 4);
        }
        if ((tid & 7) == 0) {
            int h = nt*2 + (tx >> 3);
            int bb = row >> 9;
            #pragma unroll
            for (int r = 0; r < 2; ++r) {
                int ii = (row + r) & (N-1);
                qwe[(bb*HEADS + h)*N + ii] = wep[r];
                qbe[(bb*HEADS + h)*N + ii] = bep[r];
            }
        }
    }
}

// ------------- attention v4: 2 i-rows per thread (TI=16) -------------
// block = 256 thr; lanes g=t&31 slice j; r=t>>5 gives rows i0=itile*16+r, i1=i0+8.
#define TI 16
__global__ __launch_bounds__(256, 2)
void k_attn(const float* __restrict__ qbuf, const float* __restrict__ kbuf,
            const float* __restrict__ vbuf,
            const float* __restrict__ qwe, const float* __restrict__ qbe,
            const float* __restrict__ dist,
            const float* __restrict__ We, const float* __restrict__ be,
            float* __restrict__ attnout, int layer) {
    __shared__ float Tt[32 * 128];

    int t = threadIdx.x;
    int g = t & 31;
    int r = t >> 5;                       // 0..7
    int bid = blockIdx.x;                 // (b*HEADS+h)*32 + itile
    int itile = bid & 31;
    int h = (bid >> 5) & (HEADS-1);
    int b = bid >> 8;
    int i0 = itile * TI + r;
    int i1 = i0 + 8;

    int scol = t & 127;
    int d0   = (t >> 7) * 16;

    float q0[32], q1[32];
    {
        const float4* qp0 = (const float4*)(qbuf + (size_t)(b*N + i0) * INNER + h * DHEAD);
        const float4* qp1 = (const float4*)(qbuf + (size_t)(b*N + i1) * INNER + h * DHEAD);
        #pragma unroll
        for (int c = 0; c < 8; ++c) {
            float4 v0 = qp0[c], v1 = qp1[c];
            q0[c*4+0] = v0.x; q0[c*4+1] = v0.y; q0[c*4+2] = v0.z; q0[c*4+3] = v0.w;
            q1[c*4+0] = v1.x; q1[c*4+1] = v1.y; q1[c*4+2] = v1.z; q1[c*4+3] = v1.w;
        }
    }
    float qw0 = qwe[(b*HEADS + h)*N + i0], qb0 = qbe[(b*HEADS + h)*N + i0];
    float qw1 = qwe[(b*HEADS + h)*N + i1], qb1 = qbe[(b*HEADS + h)*N + i1];

    const float* kbase = kbuf + (size_t)b*N*INNER + h*DHEAD;
    const float* vbase = vbuf + (size_t)b*N*INNER + h*DHEAD;
    const float* drow0 = dist + (size_t)(b*N + i0) * N;
    const float* drow1 = dist + (size_t)(b*N + i1) * N;

    float sim0[16], sim1[16];

    #pragma unroll
    for (int jt = 0; jt < 4; ++jt) {
        if (jt) __syncthreads();
        {   // stage K^T tile [32][128]
            const float* src = kbase + (size_t)(jt*128 + scol) * INNER + d0;
            float4 a0 = *(const float4*)(src + 0);
            float4 a1 = *(const float4*)(src + 4);
            float4 a2 = *(const float4*)(src + 8);
            float4 a3 = *(const float4*)(src + 12);
            Tt[(d0+ 0)*128 + scol] = a0.x; Tt[(d0+ 1)*128 + scol] = a0.y;
            Tt[(d0+ 2)*128 + scol] = a0.z; Tt[(d0+ 3)*128 + scol] = a0.w;
            Tt[(d0+ 4)*128 + scol] = a1.x; Tt[(d0+ 5)*128 + scol] = a1.y;
            Tt[(d0+ 6)*128 + scol] = a1.z; Tt[(d0+ 7)*128 + scol] = a1.w;
            Tt[(d0+ 8)*128 + scol] = a2.x; Tt[(d0+ 9)*128 + scol] = a2.y;
            Tt[(d0+10)*128 + scol] = a2.z; Tt[(d0+11)*128 + scol] = a2.w;
            Tt[(d0+12)*128 + scol] = a3.x; Tt[(d0+13)*128 + scol] = a3.y;
            Tt[(d0+14)*128 + scol] = a3.z; Tt[(d0+15)*128 + scol] = a3.w;
        }
        __syncthreads();
        float4 s0 = make_float4(0.f,0.f,0.f,0.f);
        float4 s1 = make_float4(0.f,0.f,0.f,0.f);
        #pragma unroll
        for (int d = 0; d < 32; ++d) {
            float4 kv = *(const float4*)&Tt[d*128 + g*4];
            float qa = q0[d], qc = q1[d];
            s0.x += qa*kv.x; s0.y += qa*kv.y; s0.z += qa*kv.z; s0.w += qa*kv.w;
            s1.x += qc*kv.x; s1.y += qc*kv.y; s1.z += qc*kv.z; s1.w += qc*kv.w;
        }
        float4 dv0 = *(const float4*)&drow0[jt*128 + g*4];
        float4 dv1 = *(const float4*)&drow1[jt*128 + g*4];
        sim0[jt*4+0] = (s0.x + dv0.x*qw0 + qb0) * SCALE;
        sim0[jt*4+1] = (s0.y + dv0.y*qw0 + qb0) * SCALE;
        sim0[jt*4+2] = (s0.z + dv0.z*qw0 + qb0) * SCALE;
        sim0[jt*4+3] = (s0.w + dv0.w*qw0 + qb0) * SCALE;
        sim1[jt*4+0] = (s1.x + dv1.x*qw1 + qb1) * SCALE;
        sim1[jt*4+1] = (s1.y + dv1.y*qw1 + qb1) * SCALE;
        sim1[jt*4+2] = (s1.z + dv1.z*qw1 + qb1) * SCALE;
        sim1[jt*4+3] = (s1.w + dv1.w*qw1 + qb1) * SCALE;
    }

    // ---- softmax (32 lanes per row) ----
    float mx0 = -1e30f, mx1 = -1e30f;
    #pragma unroll
    for (int v = 0; v < 16; ++v) { mx0 = fmaxf(mx0, sim0[v]); mx1 = fmaxf(mx1, sim1[v]); }
    #pragma unroll
    for (int o = 1; o <= 16; o <<= 1) {
        mx0 = fmaxf(mx0, __shfl_xor(mx0, o));
        mx1 = fmaxf(mx1, __shfl_xor(mx1, o));
    }

    float ls0 = 0.f, ld0 = 0.f, ls1 = 0.f, ld1 = 0.f;
    #pragma unroll
    for (int jt = 0; jt < 4; ++jt) {
        float4 dv0 = *(const float4*)&drow0[jt*128 + g*4];
        float4 dv1 = *(const float4*)&drow1[jt*128 + g*4];
        float a0[4] = {dv0.x,dv0.y,dv0.z,dv0.w};
        float a1[4] = {dv1.x,dv1.y,dv1.z,dv1.w};
        #pragma unroll
        for (int u = 0; u < 4; ++u) {
            float p0 = __expf(sim0[jt*4+u] - mx0);
            float p1 = __expf(sim1[jt*4+u] - mx1);
            sim0[jt*4+u] = p0; sim1[jt*4+u] = p1;
            ls0 += p0; ld0 += p0 * a0[u];
            ls1 += p1; ld1 += p1 * a1[u];
        }
    }
    #pragma unroll
    for (int o = 1; o <= 16; o <<= 1) {
        ls0 += __shfl_xor(ls0, o); ld0 += __shfl_xor(ld0, o);
        ls1 += __shfl_xor(ls1, o); ld1 += __shfl_xor(ld1, o);
    }

    // ---- PV ----
    float acc0[32], acc1[32];
    #pragma unroll
    for (int d = 0; d < 32; ++d) { acc0[d] = 0.f; acc1[d] = 0.f; }

    #pragma unroll
    for (int jt = 0; jt < 4; ++jt) {
        __syncthreads();
        {   // stage V^T tile
            const float* src = vbase + (size_t)(jt*128 + scol) * INNER + d0;
            float4 a0 = *(const float4*)(src + 0);
            float4 a1 = *(const float4*)(src + 4);
            float4 a2 = *(const float4*)(src + 8);
            float4 a3 = *(const float4*)(src + 12);
            Tt[(d0+ 0)*128 + scol] = a0.x; Tt[(d0+ 1)*128 + scol] = a0.y;
            Tt[(d0+ 2)*128 + scol] = a0.z; Tt[(d0+ 3)*128 + scol] = a0.w;
            Tt[(d0+ 4)*128 + scol] = a1.x; Tt[(d0+ 5)*128 + scol] = a1.y;
            Tt[(d0+ 6)*128 + scol] = a1.z; Tt[(d0+ 7)*128 + scol] = a1.w;
            Tt[(d0+ 8)*128 + scol] = a2.x; Tt[(d0+ 9)*128 + scol] = a2.y;
            Tt[(d0+10)*128 + scol] = a2.z; Tt[(d0+11)*128 + scol] = a2.w;
            Tt[(d0+12)*128 + scol] = a3.x; Tt[(d0+13)*128 + scol] = a3.y;
            Tt[(d0+14)*128 + scol] = a3.z; Tt[(d0+15)*128 + scol] = a3.w;
        }
        __syncthreads();
        float p00 = sim0[jt*4+0], p01 = sim0[jt*4+1], p02 = sim0[jt*4+2], p03 = sim0[jt*4+3];
        float p10 = sim1[jt*4+0], p11 = sim1[jt*4+1], p12 = sim1[jt*4+2], p13 = sim1[jt*4+3];
        #pragma unroll
        for (int d = 0; d < 32; ++d) {
            float4 vv = *(const float4*)&Tt[d*128 + g*4];
            acc0[d] += p00*vv.x + p01*vv.y + p02*vv.z + p03*vv.w;
            acc1[d] += p10*vv.x + p11*vv.y + p12*vv.z + p13*vv.w;
        }
    }

    #pragma unroll
    for (int d = 0; d < 32; ++d) {
        #pragma unroll
        for (int o = 1; o <= 16; o <<= 1) {
            acc0[d] += __shfl_xor(acc0[d], o);
            acc1[d] += __shfl_xor(acc1[d], o);
        }
    }

    float il0 = 1.0f / ls0, il1 = 1.0f / ls1;
    float ad0 = ld0 * il0, ad1 = ld1 * il1;
    float o0 = acc0[0], o1 = acc1[0];
    #pragma unroll
    for (int d = 1; d < 32; ++d) if (g == d) { o0 = acc0[d]; o1 = acc1[d]; }
    float wv = We[layer*INNER + h*DHEAD + g];
    float bv = be[layer*INNER + h*DHEAD + g];
    attnout[(size_t)(b*N + i0)*INNER + h*DHEAD + g] = o0*il0 + ad0*wv + bv;
    attnout[(size_t)(b*N + i1)*INNER + h*DHEAD + g] = o1*il1 + ad1*wv + bv;
}

// ------------- O GEMM: obuf = attnout @ Wo + bo -------------
__global__ __launch_bounds__(256, 4)
void k_gemm_o(const float* __restrict__ attnout, const float* __restrict__ Wo,
              const float* __restrict__ bo, float* __restrict__ obuf, int layer) {
    __shared__ float AT[64][32];
    __shared__ float Bs[64][32];
    int tid = threadIdx.x;
    int mt = blockIdx.x & 31, nt = blockIdx.x >> 5;
    int tx = tid & 7, ty = tid >> 3;

    float acc[4] = {0,0,0,0};
    int am = tid & 31, ak = tid >> 5;
    int bn4 = tid & 7, bk = tid >> 3;
    const float* Wsrc = Wo + (size_t)layer*256*256 + nt*32;

    for (int kt = 0; kt < 4; ++kt) {
        int kbase = kt * 64;
        if (kt) __syncthreads();
        {
            const float* src = attnout + (size_t)(mt*32 + am)*256 + kbase + ak*8;
            float4 a0 = *(const float4*)src;
            float4 a1 = *(const float4*)(src + 4);
            AT[ak*8+0][am]=a0.x; AT[ak*8+1][am]=a0.y; AT[ak*8+2][am]=a0.z; AT[ak*8+3][am]=a0.w;
            AT[ak*8+4][am]=a1.x; AT[ak*8+5][am]=a1.y; AT[ak*8+6][am]=a1.z; AT[ak*8+7][am]=a1.w;
        }
        #pragma unroll
        for (int p = 0; p < 2; ++p) {
            int k = bk + p*32;
            *(float4*)&Bs[k][bn4*4] = *(const float4*)(Wsrc + (size_t)(kbase + k)*256 + bn4*4);
        }
        __syncthreads();
        #pragma unroll 8
        for (int k = 0; k < 64; ++k) {
            float a = AT[k][ty];
            float4 b = *(const float4*)&Bs[k][tx*4];
            acc[0] += a*b.x; acc[1] += a*b.y; acc[2] += a*b.z; acc[3] += a*b.w;
        }
    }
    int row = mt*32 + ty, n = nt*32 + tx*4;
    float4 bias = *(const float4*)&bo[layer*256 + n];
    float4 o = make_float4(acc[0]+bias.x, acc[1]+bias.y, acc[2]+bias.z, acc[3]+bias.w);
    *(float4*)&obuf[(size_t)row*256 + n] = o;
}

// ------------- gate + residual, then LN(next) or decode -------------
__global__ void k_gate_ln(const float* __restrict__ obuf, const float* __restrict__ Wg,
                          const float* __restrict__ ln_g, const float* __restrict__ ln_b,
                          const float* __restrict__ Wdec,
                          float* __restrict__ nodes, float* __restrict__ hbuf,
                          float* __restrict__ out, int layer) {
    __shared__ float red4[4];
    int row = blockIdx.x, d = threadIdx.x;
    float o  = obuf[row*DIM + d];
    float nd = nodes[row*DIM + d];
    const float* Wgl = Wg + layer*3*DIM;
    float s = o*Wgl[d] + nd*Wgl[DIM+d] + (o-nd)*Wgl[2*DIM+d];
    float tot = block_sum256(s, red4);
    float gate = 1.0f/(1.0f + __expf(-tot));
    float nn = o*gate + nd*(1.0f - gate);
    nodes[row*DIM + d] = nn;
    if (layer == 0) {
        float mean = block_sum256(nn, red4) * (1.0f/DIM);
        float c = nn - mean;
        float var = block_sum256(c*c, red4) * (1.0f/DIM);
        hbuf[row*DIM + d] = c * (1.0f/sqrtf(var + 1e-5f)) * ln_g[DIM + d] + ln_b[DIM + d];
    } else {
        float s0 = block_sum256(nn * Wdec[d*3+0], red4);
        float s1 = block_sum256(nn * Wdec[d*3+1], red4);
        float s2 = block_sum256(nn * Wdec[d*3+2], red4);
        if (d == 0) { out[row*3+0] = s0; out[row*3+1] = s1; out[row*3+2] = s2; }
    }
}

extern "C" void kernel_launch(void* const* d_in, const int* in_sizes, int n_in,
                              void* d_out, int out_size, void* d_ws, size_t ws_size,
                              hipStream_t stream) {
    const float* x     = (const float*)d_in[0];
    const float* t     = (const float*)d_in[1];
    const float* W_enc = (const float*)d_in[2];
    const float* W_dec = (const float*)d_in[3];
    const float* ln_g  = (const float*)d_in[4];
    const float* ln_b  = (const float*)d_in[5];
    const float* Wq    = (const float*)d_in[6];
    const float* bq    = (const float*)d_in[7];
    const float* Wkv   = (const float*)d_in[8];
    const float* bkv   = (const float*)d_in[9];
    const float* We    = (const float*)d_in[10];
    const float* be    = (const float*)d_in[11];
    const float* Wo    = (const float*)d_in[12];
    const float* bo    = (const float*)d_in[13];
    const float* Wg    = (const float*)d_in[14];
    float* out = (float*)d_out;

    float* ws = (float*)d_ws;
    float* nodes   = ws;
    float* dist    = nodes   + B*N*DIM;
    float* hbuf    = dist    + B*N*N;
    float* qbuf    = hbuf    + B*N*DIM;
    float* kbuf    = qbuf    + B*N*INNER;
    float* vbuf    = kbuf    + B*N*INNER;
    float* qwe     = vbuf    + B*N*INNER;
    float* qbe     = qwe     + B*HEADS*N;
    float* attnout = qbe     + B*HEADS*N;
    float* obuf    = attnout + B*N*INNER;
    float* ct      = obuf    + B*N*DIM;
    float* st      = ct      + N*16;

    k_pre<<<B*N, DIM, 0, stream>>>(x, t, W_enc, ln_g, ln_b, nodes, hbuf, dist, ct, st);
    for (int l = 0; l < DEPTH; ++l) {
        k_gemm_qkv<<<384, 256, 0, stream>>>(hbuf, Wq, bq, Wkv, bkv, We, be, ct, st,
                                            qbuf, kbuf, vbuf, qwe, qbe, l);
        k_attn<<<B*HEADS*(N/TI), 256, 0, stream>>>(qbuf, kbuf, vbuf, qwe, qbe, dist, We, be,
                                                   attnout, l);
        k_gemm_o<<<256, 256, 0, stream>>>(attnout, Wo, bo, obuf, l);
        k_gate_ln<<<B*N, DIM, 0, stream>>>(obuf, Wg, ln_g, ln_b, W_dec, nodes, hbuf, out, l);
    }
}